// Round 14
// baseline (1225.526 us; speedup 1.0000x reference)
//
#include <hip/hip_runtime.h>

#define TT 2048
#define II 8
#define HH 24
#define THRESH 0.1f
#define LOG2E 1.4426950408889634f

typedef float v2f __attribute__((ext_vector_type(2)));

// rotate within 16-lane row by N, add (DPP row_ror, VALU-only)
#define ROR_ADD(a, N)                                                          \
    {                                                                          \
        int t_ = __builtin_amdgcn_update_dpp(0, __float_as_int(a),             \
                                             0x120 + (N), 0xF, 0xF, false);    \
        (a) += __int_as_float(t_);                                             \
    }

__device__ __forceinline__ float readlane_f(float v, int l) {
    return __int_as_float(__builtin_amdgcn_readlane(__float_as_int(v), l));
}

// One wave (= one block) per batch element; 2048 waves = 2 waves/SIMD.
//  lane l32=j<24, lo half : owns gate rows (i_j, f_j)
//  lane l32=j<24, hi half : owns gate rows (g_j, o_j)
//  lanes 24-31 (lo half)  : x-prefetch lanes (k=0..7), junk weights (clamped)
//  lanes 56-63            : junk (clamped row-0 weights), woutj=0 masks them
//
// R14 = R9 with ONLY the h-path changed:
//  - h exchange: 24 v_readlane -> SGPRs (VALU issue, no memory, no lgkmcnt)
//    replacing ds_write+lgkmcnt+8x ds_read_b128 (~240cy serial latency).
//  - x path UNCHANGED from R9: per-lane vector loads in xL lanes (vmcnt!
//    R13 lesson: uniform x loads become s_load -> HBM refetch, FETCH 2x),
//    staged via 8-float LDS written at step TOP (x for t+1 known a step
//    early -> DS latency hidden under dots+nonlin+head).
//  - dots: x-part pk-FMA (v2f), h-part scalar even/odd FMA with 1 SGPR
//    operand (legal; pairing bit-identical to R9's pk — proven in R13).
__global__ __launch_bounds__(64)
__attribute__((amdgpu_waves_per_eu(2, 2)))
void lstm_anom_kernel(const float* __restrict__ x,
                      const float* __restrict__ W_ih,
                      const float* __restrict__ W_hh,
                      const float* __restrict__ b_ih,
                      const float* __restrict__ b_hh,
                      const float* __restrict__ W_out,
                      const float* __restrict__ b_out,
                      float* __restrict__ out)
{
    __shared__ __align__(16) float vbuf[8];    // x row staging only

    const int  lane  = threadIdx.x;
    const int  b     = blockIdx.x;
    const int  l32   = lane & 31;
    const bool hi    = lane >= 32;
    const bool unitL = (l32 < HH);
    const int  jc    = unitL ? l32 : 0;        // clamped for junk lanes
    const bool xL    = (!hi) && (l32 >= 24);   // lanes 24..31
    const int  xk    = l32 - 24;

    const float* xb = x + (size_t)b * (TT * II);

    // ---- persistent weights: x-part v2f pairs, h-part scalar ----
    const int rowA = (hi ? 2 * HH : 0) + jc;   // lo: i-gate, hi: g-gate
    const int rowB = rowA + HH;                // lo: f-gate, hi: o-gate
    v2f wA2[4], wB2[4];
    {
        const float4 a0 = *(const float4*)(W_ih + rowA * II);
        const float4 a1 = *(const float4*)(W_ih + rowA * II + 4);
        const float4 b0 = *(const float4*)(W_ih + rowB * II);
        const float4 b1 = *(const float4*)(W_ih + rowB * II + 4);
        wA2[0] = (v2f){a0.x, a0.y}; wA2[1] = (v2f){a0.z, a0.w};
        wA2[2] = (v2f){a1.x, a1.y}; wA2[3] = (v2f){a1.z, a1.w};
        wB2[0] = (v2f){b0.x, b0.y}; wB2[1] = (v2f){b0.z, b0.w};
        wB2[2] = (v2f){b1.x, b1.y}; wB2[3] = (v2f){b1.z, b1.w};
    }
    float wAs[HH], wBs[HH];
    #pragma unroll
    for (int q = 0; q < 6; ++q) {              // W_hh rows: 24 floats
        const float4 qa = *(const float4*)(W_hh + rowA * HH + q * 4);
        const float4 qb = *(const float4*)(W_hh + rowB * HH + q * 4);
        wAs[q*4+0]=qa.x; wAs[q*4+1]=qa.y; wAs[q*4+2]=qa.z; wAs[q*4+3]=qa.w;
        wBs[q*4+0]=qb.x; wBs[q*4+1]=qb.y; wBs[q*4+2]=qb.z; wBs[q*4+3]=qb.w;
    }
    const float biasA = b_ih[rowA] + b_hh[rowA];
    const float biasB = b_ih[rowB] + b_hh[rowB];
    // nonlin A: lo -> sigmoid(a), hi -> tanh(a) = 2*sigmoid(2a)-1, uniform code
    const float kA = hi ? (-2.f * LOG2E) : (-LOG2E);
    const float mA = hi ? 2.f : 1.f;
    const float nA = hi ? -1.f : 0.f;
    const float woutj = unitL ? W_out[jc] : 0.f;
    const float bout  = b_out[0];

    // ---- init: v2x = x row 0 (pairs); xA = x row 1 in xL lanes; sh = 0 ----
    v2f v2x[4];
    {
        const float4 q0 = *(const float4*)(xb + 0);
        const float4 q1 = *(const float4*)(xb + 4);
        v2x[0] = (v2f){q0.x, q0.y}; v2x[1] = (v2f){q0.z, q0.w};
        v2x[2] = (v2f){q1.x, q1.y}; v2x[3] = (v2f){q1.z, q1.w};
    }
    float sh[HH];
    #pragma unroll
    for (int j = 0; j < HH; ++j) sh[j] = 0.f;       // h0 = 0
    float xA = 0.f, xB = 0.f;
    if (xL) xA = xb[II + xk];                       // x[b][1][k], per-lane load
    __syncthreads();                                // harmless once

    float pred = v2x[0].x;      // pred0 = x[b][0][0] -> no substitution at t=0
    float cst = 0.f, predsave = 0.f;

    for (int t = 0; t < TT; ++t) {
        // ---- stage NEXT x row into LDS at step top (a full step of slack)
        if (xL) vbuf[xk] = xA;

        // ---- anomaly substitution on input 0 (in registers) ----
        v2x[0].x = (fabsf(pred - v2x[0].x) > THRESH) ? pred : v2x[0].x;

        // ---- gate dots: x-part pk-FMA, h-part scalar even/odd (SGPR val) ----
        v2f accA = (v2f){biasA, 0.f};
        v2f accB = (v2f){biasB, 0.f};
        #pragma unroll
        for (int k = 0; k < 4; ++k) {
            accA = __builtin_elementwise_fma(wA2[k], v2x[k], accA);
            accB = __builtin_elementwise_fma(wB2[k], v2x[k], accB);
        }
        float aAx = accA.x, aAy = accA.y;
        float aBx = accB.x, aBy = accB.y;
        #pragma unroll
        for (int k = 0; k < 12; ++k) {
            aAx = fmaf(wAs[2*k],   sh[2*k],   aAx);
            aAy = fmaf(wAs[2*k+1], sh[2*k+1], aAy);
            aBx = fmaf(wBs[2*k],   sh[2*k],   aBx);
            aBy = fmaf(wBs[2*k+1], sh[2*k+1], aBy);
        }
        const float aA = aAx + aAy;
        const float aB = aBx + aBy;

        // ---- nonlinearities, once per gate ----
        const float sA = __builtin_amdgcn_rcpf(1.f + __builtin_amdgcn_exp2f(kA * aA));
        const float tA = fmaf(sA, mA, nA);                  // lo: sig(i), hi: tanh(g)
        const float sB = __builtin_amdgcn_rcpf(1.f + __builtin_amdgcn_exp2f(-LOG2E * aB));
                                                            // lo: sig(f), hi: sig(o)
        // ---- distribute halves: every lane gets (ig,gg,fg,og) ----
        auto rA = __builtin_amdgcn_permlane32_swap(__float_as_int(tA), __float_as_int(tA), false, false);
        auto rB = __builtin_amdgcn_permlane32_swap(__float_as_int(sB), __float_as_int(sB), false, false);
        const float ig = __int_as_float(rA[0]);
        const float gg = __int_as_float(rA[1]);
        const float fg = __int_as_float(rB[0]);
        const float og = __int_as_float(rB[1]);

        cst = fmaf(fg, cst, ig * gg);
        const float sc = __builtin_amdgcn_rcpf(1.f + __builtin_amdgcn_exp2f(-2.f * LOG2E * cst));
        const float tc = fmaf(2.f, sc, -1.f);               // tanh(c)
        const float h  = og * tc;

        // ---- h exchange: 24 v_readlane -> SGPRs (no memory, no lgkmcnt) ----
        #pragma unroll
        for (int j = 0; j < HH; ++j) sh[j] = readlane_f(h, j);

        // ---- x prefetch for t+2 (per-lane VECTOR load -> vmcnt domain) ----
        if (xL) {
            int tn = t + 2; if (tn > TT - 1) tn = TT - 1;
            xB = xb[(size_t)tn * II + xk];
        }

        // ---- head: Σ_j wout_j*h_j (permlane16 fold + 4 DPP ror-adds) ----
        float p = woutj * h;
        {
            auto r = __builtin_amdgcn_permlane16_swap(__float_as_int(p), __float_as_int(p), false, false);
            p = __int_as_float(r[0]) + __int_as_float(r[1]);
        }
        ROR_ADD(p, 8); ROR_ADD(p, 4); ROR_ADD(p, 2); ROR_ADD(p, 1);
        pred = p + bout;

        // buffer pred; coalesced 256B flush every 64 steps
        predsave = ((t & 63) == lane) ? pred : predsave;
        if ((t & 63) == 63) out[(size_t)b * TT + (t - 63) + lane] = predsave;

        // ---- reload next x row from LDS (written at step top, slack ~full
        //      step; per-wave DS pipe is in-order) ----
        {
            const float4 q0 = *(const float4*)&vbuf[0];
            const float4 q1 = *(const float4*)&vbuf[4];
            v2x[0] = (v2f){q0.x, q0.y}; v2x[1] = (v2f){q0.z, q0.w};
            v2x[2] = (v2f){q1.x, q1.y}; v2x[3] = (v2f){q1.z, q1.w};
        }
        if (xL) xA = xB;
    }
}

extern "C" void kernel_launch(void* const* d_in, const int* in_sizes, int n_in,
                              void* d_out, int out_size, void* d_ws, size_t ws_size,
                              hipStream_t stream) {
    const float* x     = (const float*)d_in[0];
    const float* W_ih  = (const float*)d_in[1];
    const float* W_hh  = (const float*)d_in[2];
    const float* b_ih  = (const float*)d_in[3];
    const float* b_hh  = (const float*)d_in[4];
    const float* W_out = (const float*)d_in[5];
    const float* b_out = (const float*)d_in[6];
    float* out = (float*)d_out;

    dim3 grid(2048);   // one wave per batch element
    dim3 block(64);
    lstm_anom_kernel<<<grid, block, 0, stream>>>(x, W_ih, W_hh, b_ih, b_hh,
                                                 W_out, b_out, out);
}

// Round 15
// 1168.890 us; speedup vs baseline: 1.0485x; 1.0485x over previous
//
#include <hip/hip_runtime.h>

#define TT 2048
#define II 8
#define HH 24
#define THRESH 0.1f
#define LOG2E 1.4426950408889634f

typedef float v2f __attribute__((ext_vector_type(2)));

// rotate within 16-lane row by N, add (DPP row_ror, VALU-only)
#define ROR_ADD(a, N)                                                          \
    {                                                                          \
        int t_ = __builtin_amdgcn_update_dpp(0, __float_as_int(a),             \
                                             0x120 + (N), 0xF, 0xF, false);    \
        (a) += __int_as_float(t_);                                             \
    }

// One wave (= one block) per batch element; 2048 waves = 2 waves/SIMD.
//  lane l32=j<24, lo half : owns gate rows (i_j, f_j) — 2 full 32-wide pk-dots
//  lane l32=j<24, hi half : owns gate rows (g_j, o_j)
//  lanes 24-31 (lo half)  : x-prefetch lanes (k=0..7), junk weights (clamped)
//  lanes 56-63            : junk (clamped row-0 weights), woutj=0 masks them
//
// R15 = R9 with the weight path moved to LDS ("manual spill space"):
// RA refuses to keep the 64 weight floats loop-resident (4 attempts: asm
// keep-alive x2, waves_per_eu, volatile -> remat or scratch every time).
// So give remat a cheap target: per-lane 272B LDS region, read back with
// 16 ds_read_b128 (1 base VGPR + imm offsets; DS pipe, no vmcnt stalls,
// no 64-bit addressing). Stride 68 dwords -> bank (4*lane+4q+d)%32 ==
// the canonical coalesced-b128 distribution (conflict-free).
// In-loop asm on the address keeps the reads per-iteration (LICM guard).
// Arithmetic bit-identical to R9. x path unchanged (per-lane loads, R9).
__global__ __launch_bounds__(64)
__attribute__((amdgpu_waves_per_eu(2, 2)))
void lstm_anom_kernel(const float* __restrict__ x,
                      const float* __restrict__ W_ih,
                      const float* __restrict__ W_hh,
                      const float* __restrict__ b_ih,
                      const float* __restrict__ b_hh,
                      const float* __restrict__ W_out,
                      const float* __restrict__ b_out,
                      float* __restrict__ out)
{
    __shared__ __align__(16) float wlds[64 * 68];  // per-lane weight stash
    __shared__ __align__(16) float vbuf[32];       // [x0..x7; h0..h23]

    const int  lane  = threadIdx.x;
    const int  b     = blockIdx.x;
    const int  l32   = lane & 31;
    const bool hi    = lane >= 32;
    const bool unitL = (l32 < HH);
    const int  jc    = unitL ? l32 : 0;        // clamped for junk lanes
    const bool xL    = (!hi) && (l32 >= 24);   // lanes 24..31
    const int  xk    = l32 - 24;

    const float* xb = x + (size_t)b * (TT * II);

    // ---- load weights once from global; stash into per-lane LDS region ----
    const int rowA = (hi ? 2 * HH : 0) + jc;   // lo: i-gate, hi: g-gate
    const int rowB = rowA + HH;                // lo: f-gate, hi: o-gate
    {
        float4 wa[8], wb[8];
        wa[0] = *(const float4*)(W_ih + rowA * II);
        wa[1] = *(const float4*)(W_ih + rowA * II + 4);
        wb[0] = *(const float4*)(W_ih + rowB * II);
        wb[1] = *(const float4*)(W_ih + rowB * II + 4);
        #pragma unroll
        for (int q = 0; q < 6; ++q) {
            wa[2 + q] = *(const float4*)(W_hh + rowA * HH + q * 4);
            wb[2 + q] = *(const float4*)(W_hh + rowB * HH + q * 4);
        }
        float* wp = &wlds[lane * 68];
        #pragma unroll
        for (int q = 0; q < 8; ++q) {
            *(float4*)(wp + 4 * q)      = wa[q];   // A chunks: bytes 0..127
            *(float4*)(wp + 32 + 4 * q) = wb[q];   // B chunks: bytes 128..255
        }
    }
    const float biasA = b_ih[rowA] + b_hh[rowA];
    const float biasB = b_ih[rowB] + b_hh[rowB];
    // nonlin A: lo -> sigmoid(a), hi -> tanh(a) = 2*sigmoid(2a)-1, uniform code
    const float kA = hi ? (-2.f * LOG2E) : (-LOG2E);
    const float mA = hi ? 2.f : 1.f;
    const float nA = hi ? -1.f : 0.f;
    const float woutj = unitL ? W_out[jc] : 0.f;
    const float bout  = b_out[0];

    // ---- init: vbuf = [x[b][0][:8]; h0 = 0]; x pipeline in xL lanes ----
    if (lane < 32) vbuf[lane] = (lane < 8) ? xb[lane] : 0.f;
    float xA = 0.f, xB = 0.f;
    if (xL) xA = xb[II + xk];                  // x[b][1][k], per-lane load
    __syncthreads();                           // once, before the loop

    v2f v2r[16];
    #pragma unroll
    for (int c8 = 0; c8 < 8; ++c8) {
        const float4 q = *(const float4*)&vbuf[c8 * 4];
        v2r[c8 * 2]     = (v2f){q.x, q.y};
        v2r[c8 * 2 + 1] = (v2f){q.z, q.w};
    }
    float pred = v2r[0].x;      // pred0 = x[b][0][0] -> no substitution at t=0
    float cst = 0.f, predsave = 0.f;

    const int wbase0 = lane * 68;

    for (int t = 0; t < TT; ++t) {
        // launder the weight base each iteration: loads stay in-loop (the
        // cheap LDS remat we WANT), never hoisted into 64 live registers
        int wofs = wbase0;
        asm volatile("" : "+v"(wofs));
        const float4* wpa = (const float4*)&wlds[wofs];

        // anomaly substitution on input 0 (wave-uniform, in registers)
        v2r[0].x = (fabsf(pred - v2r[0].x) > THRESH) ? pred : v2r[0].x;

        // ---- 2 full 32-wide gate dots, pk-FMA; weights via ds_read_b128 ----
        v2f accA = (v2f){biasA, 0.f};
        v2f accB = (v2f){biasB, 0.f};
        #pragma unroll
        for (int q = 0; q < 8; ++q) {
            const float4 wa = wpa[q];
            const float4 wb = wpa[8 + q];
            accA = __builtin_elementwise_fma((v2f){wa.x, wa.y}, v2r[2*q],   accA);
            accA = __builtin_elementwise_fma((v2f){wa.z, wa.w}, v2r[2*q+1], accA);
            accB = __builtin_elementwise_fma((v2f){wb.x, wb.y}, v2r[2*q],   accB);
            accB = __builtin_elementwise_fma((v2f){wb.z, wb.w}, v2r[2*q+1], accB);
        }
        const float aA = accA.x + accA.y;
        const float aB = accB.x + accB.y;

        // ---- nonlinearities, once per gate ----
        const float sA = __builtin_amdgcn_rcpf(1.f + __builtin_amdgcn_exp2f(kA * aA));
        const float tA = fmaf(sA, mA, nA);                  // lo: sig(i), hi: tanh(g)
        const float sB = __builtin_amdgcn_rcpf(1.f + __builtin_amdgcn_exp2f(-LOG2E * aB));
                                                            // lo: sig(f), hi: sig(o)
        // ---- distribute halves: every lane gets (ig,gg,fg,og) ----
        auto rA = __builtin_amdgcn_permlane32_swap(__float_as_int(tA), __float_as_int(tA), false, false);
        auto rB = __builtin_amdgcn_permlane32_swap(__float_as_int(sB), __float_as_int(sB), false, false);
        const float ig = __int_as_float(rA[0]);
        const float gg = __int_as_float(rA[1]);
        const float fg = __int_as_float(rB[0]);
        const float og = __int_as_float(rB[1]);

        cst = fmaf(fg, cst, ig * gg);
        const float sc = __builtin_amdgcn_rcpf(1.f + __builtin_amdgcn_exp2f(-2.f * LOG2E * cst));
        const float tc = fmaf(2.f, sc, -1.f);               // tanh(c)
        const float h  = og * tc;

        // ---- stage next step's inputs: lanes 0-23 write h, 24-31 write x ----
        // banks 0..31 distinct, conflict-free; same-wave DS pipe is in-order
        if (lane < 32) vbuf[xL ? xk : (8 + l32)] = xL ? xA : h;
        if (xL) {                                // per-lane VECTOR load (vmcnt)
            int tn = t + 2; if (tn > TT - 1) tn = TT - 1;
            xB = xb[(size_t)tn * II + xk];
        }

        // ---- head: Σ_j wout_j*h_j (permlane16 fold + 4 DPP ror-adds) ----
        float p = woutj * h;
        {
            auto r = __builtin_amdgcn_permlane16_swap(__float_as_int(p), __float_as_int(p), false, false);
            p = __int_as_float(r[0]) + __int_as_float(r[1]);
        }
        ROR_ADD(p, 8); ROR_ADD(p, 4); ROR_ADD(p, 2); ROR_ADD(p, 1);
        pred = p + bout;

        // buffer pred; coalesced 256B flush every 64 steps
        predsave = ((t & 63) == lane) ? pred : predsave;
        if ((t & 63) == 63) out[(size_t)b * TT + (t - 63) + lane] = predsave;

        // ---- reload v for next step (broadcast ds_read_b128, DS-only) ----
        #pragma unroll
        for (int c8 = 0; c8 < 8; ++c8) {
            const float4 q = *(const float4*)&vbuf[c8 * 4];
            v2r[c8 * 2]     = (v2f){q.x, q.y};
            v2r[c8 * 2 + 1] = (v2f){q.z, q.w};
        }
        if (xL) xA = xB;
    }
}

extern "C" void kernel_launch(void* const* d_in, const int* in_sizes, int n_in,
                              void* d_out, int out_size, void* d_ws, size_t ws_size,
                              hipStream_t stream) {
    const float* x     = (const float*)d_in[0];
    const float* W_ih  = (const float*)d_in[1];
    const float* W_hh  = (const float*)d_in[2];
    const float* b_ih  = (const float*)d_in[3];
    const float* b_hh  = (const float*)d_in[4];
    const float* W_out = (const float*)d_in[5];
    const float* b_out = (const float*)d_in[6];
    float* out = (float*)d_out;

    dim3 grid(2048);   // one wave per batch element
    dim3 block(64);
    lstm_anom_kernel<<<grid, block, 0, stream>>>(x, W_ih, W_hh, b_ih, b_hh,
                                                 W_out, b_out, out);
}

// Round 16
// 724.353 us; speedup vs baseline: 1.6919x; 1.6137x over previous
//
#include <hip/hip_runtime.h>

#define TT 2048
#define II 8
#define HH 24
#define THRESH 0.1f
#define LOG2E 1.4426950408889634f

typedef float v2f __attribute__((ext_vector_type(2)));

__device__ __forceinline__ float readlane_f(float v, int l) {
    return __int_as_float(__builtin_amdgcn_readlane(__float_as_int(v), l));
}

// One wave (= one block) per batch element; 2048 waves = 2 waves/SIMD.
//  lane l32=j<24, lo half : gate rows (i_j, f_j) — full 32-wide pk-dots
//  lane l32=j<24, hi half : gate rows (g_j, o_j)
//  lane 24                : PRED ROW — wA = [0(8); W_out(24)], biasA = b_out.
//                           Its dot result IS pred(t-1); broadcast by readlane.
//  lanes 25-28 / 57-60    : x-prefetch lanes (k=0..3 / 4..7)
//  other lanes            : junk (clamped row-0 weights)
//
// R16 = R9 with the head folded into the dot phase:
//  - w[0] excluded from stored weights (kept as scalar w0A/w0B); after the
//    dot, pred is read from lane 24, the anomaly select runs mid-step, and
//    w0*v0 is added post-fold (reassociation-safe, proven R5/R9/R10).
//  - removes ~12 head instrs AND the serial permlane16+4xDPP tail from the
//    pred -> v0 -> next-dot critical path.
//  - outputs shift: pred(t-1) materializes at step t; epilogue does pred(TT-1).
// x path unchanged from R9 (per-lane vector loads -> vmcnt; LDS staging).
__global__ __launch_bounds__(64)
__attribute__((amdgpu_waves_per_eu(2, 2)))
void lstm_anom_kernel(const float* __restrict__ x,
                      const float* __restrict__ W_ih,
                      const float* __restrict__ W_hh,
                      const float* __restrict__ b_ih,
                      const float* __restrict__ b_hh,
                      const float* __restrict__ W_out,
                      const float* __restrict__ b_out,
                      float* __restrict__ out)
{
    __shared__ __align__(16) float vbuf[32];   // [x0..x7; h0..h23]

    const int  lane  = threadIdx.x;
    const int  b     = blockIdx.x;
    const int  l32   = lane & 31;
    const bool hi    = lane >= 32;
    const int  jc    = (l32 < HH) ? l32 : 0;   // clamped for junk lanes
    const bool xLn   = (l32 >= 25 && l32 <= 28);   // 8 x lanes (both halves)
    const int  xk    = (l32 - 25) + (hi ? 4 : 0);  // 0..7

    const float* xb = x + (size_t)b * (TT * II);

    // ---- persistent weights: 2 full gate rows per lane ----
    const int rowA = (hi ? 2 * HH : 0) + jc;   // lo: i-gate, hi: g-gate
    const int rowB = rowA + HH;                // lo: f-gate, hi: o-gate
    float wAf[32], wBf[32];
    #pragma unroll
    for (int q = 0; q < 2; ++q) {
        const float4 qa = *(const float4*)(W_ih + rowA * II + q * 4);
        const float4 qb = *(const float4*)(W_ih + rowB * II + q * 4);
        wAf[q*4+0]=qa.x; wAf[q*4+1]=qa.y; wAf[q*4+2]=qa.z; wAf[q*4+3]=qa.w;
        wBf[q*4+0]=qb.x; wBf[q*4+1]=qb.y; wBf[q*4+2]=qb.z; wBf[q*4+3]=qb.w;
    }
    #pragma unroll
    for (int q = 0; q < 6; ++q) {
        const float4 qa = *(const float4*)(W_hh + rowA * HH + q * 4);
        const float4 qb = *(const float4*)(W_hh + rowB * HH + q * 4);
        wAf[8+q*4+0]=qa.x; wAf[8+q*4+1]=qa.y; wAf[8+q*4+2]=qa.z; wAf[8+q*4+3]=qa.w;
        wBf[8+q*4+0]=qb.x; wBf[8+q*4+1]=qb.y; wBf[8+q*4+2]=qb.z; wBf[8+q*4+3]=qb.w;
    }
    float biasA = b_ih[rowA] + b_hh[rowA];
    float biasB = b_ih[rowB] + b_hh[rowB];
    const float bout = b_out[0];
    // exclude k=0 from the stored dot; keep as separate scalar (added post-fold)
    float w0A = wAf[0], w0B = wBf[0];
    wAf[0] = 0.f; wBf[0] = 0.f;
    if (lane == 24) {                          // PRED row
        #pragma unroll
        for (int k = 0; k < 32; ++k) { wAf[k] = 0.f; wBf[k] = 0.f; }
        #pragma unroll
        for (int j = 0; j < HH; ++j) wAf[8 + j] = W_out[j];
        biasA = bout; biasB = 0.f; w0A = 0.f; w0B = 0.f;
    }
    v2f wA2[16], wB2[16];
    #pragma unroll
    for (int k = 0; k < 16; ++k) {
        wA2[k] = (v2f){ wAf[2*k], wAf[2*k+1] };
        wB2[k] = (v2f){ wBf[2*k], wBf[2*k+1] };
    }
    // nonlin A: lo -> sigmoid(a), hi -> tanh(a) = 2*sigmoid(2a)-1, uniform code
    const float kA = hi ? (-2.f * LOG2E) : (-LOG2E);
    const float mA = hi ? 2.f : 1.f;
    const float nA = hi ? -1.f : 0.f;

    // ---- init: vbuf = [x[b][0][:8]; h0 = 0]; x pipeline in x lanes ----
    if (lane < 32) vbuf[lane] = (lane < 8) ? xb[lane] : 0.f;
    float xA = 0.f, xB = 0.f;
    if (xLn) xA = xb[II + xk];                 // x[b][1][k], per-lane load
    __syncthreads();                           // once, before the loop

    v2f v2r[16];
    #pragma unroll
    for (int c8 = 0; c8 < 8; ++c8) {
        const float4 q = *(const float4*)&vbuf[c8 * 4];
        v2r[c8 * 2]     = (v2f){q.x, q.y};
        v2r[c8 * 2 + 1] = (v2f){q.z, q.w};
    }
    float cst = 0.f, predsave = 0.f;

    for (int t = 0; t < TT; ++t) {
        // ---- 2 full 32-wide gate dots per lane (k=0 excluded), pk-FMA ----
        v2f accA = (v2f){biasA, 0.f};
        v2f accB = (v2f){biasB, 0.f};
        #pragma unroll
        for (int k = 0; k < 16; ++k) {
            accA = __builtin_elementwise_fma(wA2[k], v2r[k], accA);
            accB = __builtin_elementwise_fma(wB2[k], v2r[k], accB);
        }
        float aA = accA.x + accA.y;
        float aB = accB.x + accB.y;

        // ---- pred(t-1) falls out of lane 24's dot; anomaly select; w0 add ----
        const float x0    = v2r[0].x;                    // raw x[b][t][0]
        const float predR = readlane_f(aA, 24);
        const float predS = (t == 0) ? x0 : predR;       // pred0 = x0 -> no sub
        const float v0    = (fabsf(predS - x0) > THRESH) ? predS : x0;
        aA = fmaf(w0A, v0, aA);
        aB = fmaf(w0B, v0, aB);

        // ---- nonlinearities, once per gate ----
        const float sA = __builtin_amdgcn_rcpf(1.f + __builtin_amdgcn_exp2f(kA * aA));
        const float tA = fmaf(sA, mA, nA);               // lo: sig(i), hi: tanh(g)
        const float sB = __builtin_amdgcn_rcpf(1.f + __builtin_amdgcn_exp2f(-LOG2E * aB));
                                                         // lo: sig(f), hi: sig(o)
        // ---- distribute halves: every lane gets (ig,gg,fg,og) ----
        auto rA = __builtin_amdgcn_permlane32_swap(__float_as_int(tA), __float_as_int(tA), false, false);
        auto rB = __builtin_amdgcn_permlane32_swap(__float_as_int(sB), __float_as_int(sB), false, false);
        const float ig = __int_as_float(rA[0]);
        const float gg = __int_as_float(rA[1]);
        const float fg = __int_as_float(rB[0]);
        const float og = __int_as_float(rB[1]);

        cst = fmaf(fg, cst, ig * gg);
        const float sc = __builtin_amdgcn_rcpf(1.f + __builtin_amdgcn_exp2f(-2.f * LOG2E * cst));
        const float tc = fmaf(2.f, sc, -1.f);            // tanh(c)
        const float h  = og * tc;

        // ---- record pred(t-1); flush 64 at a time (coalesced 256B) ----
        predsave = (((t - 1) & 63) == lane) ? predS : predsave;  // t=0 slot63 bogus, overwritten at t=64 pre-flush
        if (t && (t & 63) == 0) out[(size_t)b * TT + (t - 64) + lane] = predsave;

        // ---- stage next step's inputs (banks distinct, conflict-free) ----
        if (lane < HH || xLn) vbuf[xLn ? xk : (8 + l32)] = xLn ? xA : h;
        if (xLn) {                               // per-lane VECTOR load (vmcnt)
            int tn = t + 2; if (tn > TT - 1) tn = TT - 1;
            xB = xb[(size_t)tn * II + xk];
        }

        // ---- reload v for next step (broadcast ds_read_b128, DS-only) ----
        #pragma unroll
        for (int c8 = 0; c8 < 8; ++c8) {
            const float4 q = *(const float4*)&vbuf[c8 * 4];
            v2r[c8 * 2]     = (v2f){q.x, q.y};
            v2r[c8 * 2 + 1] = (v2f){q.z, q.w};
        }
        if (xLn) xA = xB;
    }

    // ---- epilogue: pred(TT-1) from h(TT-1) (in v2r now); final flush ----
    {
        v2f accA = (v2f){biasA, 0.f};
        #pragma unroll
        for (int k = 0; k < 16; ++k)
            accA = __builtin_elementwise_fma(wA2[k], v2r[k], accA);
        const float predL = readlane_f(accA.x + accA.y, 24);
        predsave = (lane == 63) ? predL : predsave;
        out[(size_t)b * TT + (TT - 64) + lane] = predsave;
    }
}

extern "C" void kernel_launch(void* const* d_in, const int* in_sizes, int n_in,
                              void* d_out, int out_size, void* d_ws, size_t ws_size,
                              hipStream_t stream) {
    const float* x     = (const float*)d_in[0];
    const float* W_ih  = (const float*)d_in[1];
    const float* W_hh  = (const float*)d_in[2];
    const float* b_ih  = (const float*)d_in[3];
    const float* b_hh  = (const float*)d_in[4];
    const float* W_out = (const float*)d_in[5];
    const float* b_out = (const float*)d_in[6];
    float* out = (float*)d_out;

    dim3 grid(2048);   // one wave per batch element
    dim3 block(64);
    lstm_anom_kernel<<<grid, block, 0, stream>>>(x, W_ih, W_hh, b_ih, b_hh,
                                                 W_out, b_out, out);
}

// Round 18
// 684.532 us; speedup vs baseline: 1.7903x; 1.0582x over previous
//
#include <hip/hip_runtime.h>

#define TT 2048
#define II 8
#define HH 24
#define THRESH 0.1f
#define LOG2E 1.4426950408889634f

typedef float v2f __attribute__((ext_vector_type(2)));

__device__ __forceinline__ float readlane_f(float v, int l) {
    return __int_as_float(__builtin_amdgcn_readlane(__float_as_int(v), l));
}

// One wave (= one block) per batch element; 2048 waves = 2 waves/SIMD.
//  lane l32=j<24, lo half : gate rows (i_j, f_j) — full 32-wide pk-dots
//  lane l32=j<24, hi half : gate rows (g_j, o_j)
//  lane 24                : PRED ROW — wA = [0(8); W_out(24)], biasA = b_out
//  lanes 25-28 / 57-60    : x lanes (k=0..3 / 4..7)
//
// R18 = R16 body VERBATIM, loop unrolled x8 (bisects R17's failure: R17
// changed unroll AND x-chunking at once and failed; this isolates the
// unroll). Semantically a pure unroll -> must be bit-identical to R16.
// Perf upside: compiler may pipeline step s+1's 16 weight loads into step
// s's nonlinearity phase (can't across a rolled back-edge).
__global__ __launch_bounds__(64)
__attribute__((amdgpu_waves_per_eu(2, 2)))
void lstm_anom_kernel(const float* __restrict__ x,
                      const float* __restrict__ W_ih,
                      const float* __restrict__ W_hh,
                      const float* __restrict__ b_ih,
                      const float* __restrict__ b_hh,
                      const float* __restrict__ W_out,
                      const float* __restrict__ b_out,
                      float* __restrict__ out)
{
    __shared__ __align__(16) float vbuf[32];   // [x0..x7; h0..h23]

    const int  lane  = threadIdx.x;
    const int  b     = blockIdx.x;
    const int  l32   = lane & 31;
    const bool hi    = lane >= 32;
    const int  jc    = (l32 < HH) ? l32 : 0;   // clamped for junk lanes
    const bool xLn   = (l32 >= 25 && l32 <= 28);   // 8 x lanes (both halves)
    const int  xk    = (l32 - 25) + (hi ? 4 : 0);  // 0..7

    const float* xb = x + (size_t)b * (TT * II);

    // ---- persistent weights: 2 full gate rows per lane ----
    const int rowA = (hi ? 2 * HH : 0) + jc;   // lo: i-gate, hi: g-gate
    const int rowB = rowA + HH;                // lo: f-gate, hi: o-gate
    float wAf[32], wBf[32];
    #pragma unroll
    for (int q = 0; q < 2; ++q) {
        const float4 qa = *(const float4*)(W_ih + rowA * II + q * 4);
        const float4 qb = *(const float4*)(W_ih + rowB * II + q * 4);
        wAf[q*4+0]=qa.x; wAf[q*4+1]=qa.y; wAf[q*4+2]=qa.z; wAf[q*4+3]=qa.w;
        wBf[q*4+0]=qb.x; wBf[q*4+1]=qb.y; wBf[q*4+2]=qb.z; wBf[q*4+3]=qb.w;
    }
    #pragma unroll
    for (int q = 0; q < 6; ++q) {
        const float4 qa = *(const float4*)(W_hh + rowA * HH + q * 4);
        const float4 qb = *(const float4*)(W_hh + rowB * HH + q * 4);
        wAf[8+q*4+0]=qa.x; wAf[8+q*4+1]=qa.y; wAf[8+q*4+2]=qa.z; wAf[8+q*4+3]=qa.w;
        wBf[8+q*4+0]=qb.x; wBf[8+q*4+1]=qb.y; wBf[8+q*4+2]=qb.z; wBf[8+q*4+3]=qb.w;
    }
    float biasA = b_ih[rowA] + b_hh[rowA];
    float biasB = b_ih[rowB] + b_hh[rowB];
    const float bout = b_out[0];
    // exclude k=0 from the stored dot; keep as separate scalar (added post-fold)
    float w0A = wAf[0], w0B = wBf[0];
    wAf[0] = 0.f; wBf[0] = 0.f;
    if (lane == 24) {                          // PRED row
        #pragma unroll
        for (int k = 0; k < 32; ++k) { wAf[k] = 0.f; wBf[k] = 0.f; }
        #pragma unroll
        for (int j = 0; j < HH; ++j) wAf[8 + j] = W_out[j];
        biasA = bout; biasB = 0.f; w0A = 0.f; w0B = 0.f;
    }
    v2f wA2[16], wB2[16];
    #pragma unroll
    for (int k = 0; k < 16; ++k) {
        wA2[k] = (v2f){ wAf[2*k], wAf[2*k+1] };
        wB2[k] = (v2f){ wBf[2*k], wBf[2*k+1] };
    }
    // nonlin A: lo -> sigmoid(a), hi -> tanh(a) = 2*sigmoid(2a)-1, uniform code
    const float kA = hi ? (-2.f * LOG2E) : (-LOG2E);
    const float mA = hi ? 2.f : 1.f;
    const float nA = hi ? -1.f : 0.f;

    // ---- init: vbuf = [x[b][0][:8]; h0 = 0]; x pipeline in x lanes ----
    if (lane < 32) vbuf[lane] = (lane < 8) ? xb[lane] : 0.f;
    float xA = 0.f, xB = 0.f;
    if (xLn) xA = xb[II + xk];                 // x[b][1][k], per-lane load
    __syncthreads();                           // once, before the loop

    v2f v2r[16];
    #pragma unroll
    for (int c8 = 0; c8 < 8; ++c8) {
        const float4 q = *(const float4*)&vbuf[c8 * 4];
        v2r[c8 * 2]     = (v2f){q.x, q.y};
        v2r[c8 * 2 + 1] = (v2f){q.z, q.w};
    }
    float cst = 0.f, predsave = 0.f;

    for (int t8 = 0; t8 < TT; t8 += 8) {
        #pragma unroll
        for (int s = 0; s < 8; ++s) {
            const int t = t8 + s;

            // ---- 2 full 32-wide gate dots per lane (k=0 excluded), pk-FMA ----
            v2f accA = (v2f){biasA, 0.f};
            v2f accB = (v2f){biasB, 0.f};
            #pragma unroll
            for (int k = 0; k < 16; ++k) {
                accA = __builtin_elementwise_fma(wA2[k], v2r[k], accA);
                accB = __builtin_elementwise_fma(wB2[k], v2r[k], accB);
            }
            float aA = accA.x + accA.y;
            float aB = accB.x + accB.y;

            // ---- pred(t-1) from lane 24's dot; anomaly select; w0 add ----
            const float x0    = v2r[0].x;                    // raw x[b][t][0]
            const float predR = readlane_f(aA, 24);
            const float predS = (t == 0) ? x0 : predR;       // pred0 = x0
            const float v0    = (fabsf(predS - x0) > THRESH) ? predS : x0;
            aA = fmaf(w0A, v0, aA);
            aB = fmaf(w0B, v0, aB);

            // ---- nonlinearities, once per gate ----
            const float sA = __builtin_amdgcn_rcpf(1.f + __builtin_amdgcn_exp2f(kA * aA));
            const float tA = fmaf(sA, mA, nA);               // lo: sig(i), hi: tanh(g)
            const float sB = __builtin_amdgcn_rcpf(1.f + __builtin_amdgcn_exp2f(-LOG2E * aB));
                                                             // lo: sig(f), hi: sig(o)
            // ---- distribute halves: every lane gets (ig,gg,fg,og) ----
            auto rA = __builtin_amdgcn_permlane32_swap(__float_as_int(tA), __float_as_int(tA), false, false);
            auto rB = __builtin_amdgcn_permlane32_swap(__float_as_int(sB), __float_as_int(sB), false, false);
            const float ig = __int_as_float(rA[0]);
            const float gg = __int_as_float(rA[1]);
            const float fg = __int_as_float(rB[0]);
            const float og = __int_as_float(rB[1]);

            cst = fmaf(fg, cst, ig * gg);
            const float sc = __builtin_amdgcn_rcpf(1.f + __builtin_amdgcn_exp2f(-2.f * LOG2E * cst));
            const float tc = fmaf(2.f, sc, -1.f);            // tanh(c)
            const float h  = og * tc;

            // ---- record pred(t-1); flush 64 at a time (coalesced 256B) ----
            predsave = (((t - 1) & 63) == lane) ? predS : predsave;
            if (t && (t & 63) == 0)
                out[(size_t)b * TT + (t - 64) + lane] = predsave;

            // ---- stage next step's inputs (banks distinct, conflict-free) ----
            if (lane < HH || xLn) vbuf[xLn ? xk : (8 + l32)] = xLn ? xA : h;
            if (xLn) {                           // per-lane VECTOR load (vmcnt)
                int tn = t + 2; if (tn > TT - 1) tn = TT - 1;
                xB = xb[(size_t)tn * II + xk];
            }

            // ---- reload v for next step (broadcast ds_read_b128, DS-only) ----
            #pragma unroll
            for (int c8 = 0; c8 < 8; ++c8) {
                const float4 q = *(const float4*)&vbuf[c8 * 4];
                v2r[c8 * 2]     = (v2f){q.x, q.y};
                v2r[c8 * 2 + 1] = (v2f){q.z, q.w};
            }
            if (xLn) xA = xB;
        }
    }

    // ---- epilogue: pred(TT-1) from h(TT-1) (in v2r now); final flush ----
    {
        v2f accA = (v2f){biasA, 0.f};
        #pragma unroll
        for (int k = 0; k < 16; ++k)
            accA = __builtin_elementwise_fma(wA2[k], v2r[k], accA);
        const float predL = readlane_f(accA.x + accA.y, 24);
        predsave = (lane == 63) ? predL : predsave;
        out[(size_t)b * TT + (TT - 64) + lane] = predsave;
    }
}

extern "C" void kernel_launch(void* const* d_in, const int* in_sizes, int n_in,
                              void* d_out, int out_size, void* d_ws, size_t ws_size,
                              hipStream_t stream) {
    const float* x     = (const float*)d_in[0];
    const float* W_ih  = (const float*)d_in[1];
    const float* W_hh  = (const float*)d_in[2];
    const float* b_ih  = (const float*)d_in[3];
    const float* b_hh  = (const float*)d_in[4];
    const float* W_out = (const float*)d_in[5];
    const float* b_out = (const float*)d_in[6];
    float* out = (float*)d_out;

    dim3 grid(2048);   // one wave per batch element
    dim3 block(64);
    lstm_anom_kernel<<<grid, block, 0, stream>>>(x, W_ih, W_hh, b_ih, b_hh,
                                                 W_out, b_out, out);
}